// Round 1
// baseline (92.349 us; speedup 1.0000x reference)
//
#include <hip/hip_runtime.h>

// Affine-scan parallelization of a linear RK4 recurrence.
// s = [y0, y1, v0, v1];  s_{t+1} = A s_t + B u_t  (A 4x4, B 4x2 constant).
//
// L_CHUNK = 64 steps/chunk (power of 2 so chunk matrix = A^64 = 6 squarings),
// NCHUNK = 2048 chunks (covers T up to 131072), scan = 256 segments x 8 chunks.

#define L_LOG2   6
#define L_CHUNK  64
#define SEG      8
#define NSEG     256
#define NCHUNK   (NSEG * SEG)   // 2048
#define SMAX     16             // need A^(2^16) for top scan level
#define NLEV     (SMAX - L_LOG2 + 1)  // table S6..S16 -> 11 entries

// ---------------- f64 exact one-step RK4 map ----------------
__device__ inline void accel_d(const double* M, const double* Cm, const double* Km,
                               const double* u, const double* z, const double* v, double* a) {
  a[0] = (u[0] - Cm[0] * v[0] - Cm[1] * v[1] - Km[0] * z[0] - Km[1] * z[1]) / M[0];
  a[1] = (u[1] - Cm[2] * v[0] - Cm[3] * v[1] - Km[2] * z[0] - Km[3] * z[1]) / M[1];
}

__device__ inline void rk4_step_d(const double* M, const double* Cm, const double* Km,
                                  double dt, double* y, double* v, const double* u) {
  double k1[2], k2[2], k3[2], k4[2];
  double y2[2], v2[2], y3[2], v3[2], y4[2], v4[2];
  double h = dt * 0.5;
  accel_d(M, Cm, Km, u, y, v, k1);
  y2[0] = y[0] + v[0] * h;  y2[1] = y[1] + v[1] * h;
  v2[0] = v[0] + k1[0] * h; v2[1] = v[1] + k1[1] * h;
  accel_d(M, Cm, Km, u, y2, v2, k2);
  y3[0] = y[0] + v2[0] * h;  y3[1] = y[1] + v2[1] * h;
  v3[0] = v[0] + k2[0] * h;  v3[1] = v[1] + k2[1] * h;
  accel_d(M, Cm, Km, u, y3, v3, k3);
  y4[0] = y[0] + v3[0] * dt; y4[1] = y[1] + v3[1] * dt;
  v4[0] = v[0] + k3[0] * dt; v4[1] = v[1] + k3[1] * dt;
  accel_d(M, Cm, Km, u, y4, v4, k4);
  double s = dt / 6.0;
  double yn0 = y[0] + s * (v[0] + 2.0 * v2[0] + 2.0 * v3[0] + v4[0]);
  double yn1 = y[1] + s * (v[1] + 2.0 * v2[1] + 2.0 * v3[1] + v4[1]);
  double vn0 = v[0] + s * (k1[0] + 2.0 * k2[0] + 2.0 * k3[0] + k4[0]);
  double vn1 = v[1] + s * (k1[1] + 2.0 * k2[1] + 2.0 * k3[1] + k4[1]);
  y[0] = yn0; y[1] = yn1; v[0] = vn0; v[1] = vn1;
}

// threads 0..5 build columns of A (basis states) / B (basis inputs) in f64,
// store f32 copies (Af/Bf) and/or f64 copy (Ad) to LDS. Null ptrs skipped.
__device__ inline void build_cols(const float* Mp, const float* Cp, const float* Kp,
                                  const float* dtp, float* Af, float* Bf, double* Ad) {
  int tid = threadIdx.x;
  if (tid < 6) {
    double M[2]  = {(double)Mp[0], (double)Mp[1]};
    double Cm[4] = {(double)Cp[0] + (double)Cp[1], -(double)Cp[1],
                    -(double)Cp[1], (double)Cp[2] + (double)Cp[1]};
    double Km[4] = {(double)Kp[0] + (double)Kp[1], -(double)Kp[1],
                    -(double)Kp[1], (double)Kp[2] + (double)Kp[1]};
    double dt = (double)dtp[0];
    double y[2] = {0, 0}, v[2] = {0, 0}, u[2] = {0, 0};
    if      (tid == 0) y[0] = 1.0;
    else if (tid == 1) y[1] = 1.0;
    else if (tid == 2) v[0] = 1.0;
    else if (tid == 3) v[1] = 1.0;
    else if (tid == 4) u[0] = 1.0;
    else               u[1] = 1.0;
    rk4_step_d(M, Cm, Km, dt, y, v, u);
    if (tid < 4) {
      if (Af) {
        Af[0 * 4 + tid] = (float)y[0]; Af[1 * 4 + tid] = (float)y[1];
        Af[2 * 4 + tid] = (float)v[0]; Af[3 * 4 + tid] = (float)v[1];
      }
      if (Ad) {
        Ad[0 * 4 + tid] = y[0]; Ad[1 * 4 + tid] = y[1];
        Ad[2 * 4 + tid] = v[0]; Ad[3 * 4 + tid] = v[1];
      }
    } else if (Bf) {
      int j = tid - 4;
      Bf[0 * 2 + j] = (float)y[0]; Bf[1 * 2 + j] = (float)y[1];
      Bf[2 * 2 + j] = (float)v[0]; Bf[3 * 2 + j] = (float)v[1];
    }
  }
}

// ---------------- f32 helpers ----------------
__device__ inline float4 mv4(const float* A, float4 x) {
  float4 r;
  r.x = A[0]  * x.x + A[1]  * x.y + A[2]  * x.z + A[3]  * x.w;
  r.y = A[4]  * x.x + A[5]  * x.y + A[6]  * x.z + A[7]  * x.w;
  r.z = A[8]  * x.x + A[9]  * x.y + A[10] * x.z + A[11] * x.w;
  r.w = A[12] * x.x + A[13] * x.y + A[14] * x.z + A[15] * x.w;
  return r;
}
__device__ inline float4 f4add(float4 a, float4 b) {
  return make_float4(a.x + b.x, a.y + b.y, a.z + b.z, a.w + b.w);
}
__device__ inline float4 stepf(const float* a, const float* b, float4 s, float2 ut) {
  float4 r;
  r.x = a[0]  * s.x + a[1]  * s.y + a[2]  * s.z + a[3]  * s.w + b[0] * ut.x + b[1] * ut.y;
  r.y = a[4]  * s.x + a[5]  * s.y + a[6]  * s.z + a[7]  * s.w + b[2] * ut.x + b[3] * ut.y;
  r.z = a[8]  * s.x + a[9]  * s.y + a[10] * s.z + a[11] * s.w + b[4] * ut.x + b[5] * ut.y;
  r.w = a[12] * s.x + a[13] * s.y + a[14] * s.z + a[15] * s.w + b[6] * ut.x + b[7] * ut.y;
  return r;
}

// ---------------- Kernel A: per-chunk affine offsets ----------------
__global__ __launch_bounds__(256) void kOffsets(
    const float* __restrict__ u, const float* M, const float* C, const float* K,
    const float* dtp, int T, float4* __restrict__ c_arr) {
  __shared__ float Af[16], Bf[8];
  build_cols(M, C, K, dtp, Af, Bf, nullptr);
  __syncthreads();
  float a[16], b[8];
#pragma unroll
  for (int e = 0; e < 16; ++e) a[e] = Af[e];
#pragma unroll
  for (int e = 0; e < 8; ++e) b[e] = Bf[e];

  int j  = blockIdx.x * blockDim.x + threadIdx.x;  // chunk id
  int t0 = j * L_CHUNK;
  const float2* u2 = (const float2*)u;
  float4 c = make_float4(0.f, 0.f, 0.f, 0.f);
  if (t0 + L_CHUNK <= T) {
#pragma unroll 4
    for (int i = 0; i < L_CHUNK; ++i) c = stepf(a, b, c, u2[t0 + i]);
  } else {
    for (int i = 0; i < L_CHUNK; ++i) {
      int t = t0 + i;
      if (t >= T) break;
      c = stepf(a, b, c, u2[t]);
    }
  }
  c_arr[j] = c;  // empty chunks write 0 (identity offset)
}

// ---------------- Kernel B: power table + block scan -> chunk start states ----------------
__global__ __launch_bounds__(NSEG) void kScan(
    const float* M, const float* C, const float* K, const float* dtp,
    const float* x0, int T, const float4* __restrict__ c_arr, float4* __restrict__ s_arr) {
  __shared__ double Ad[16];
  __shared__ float  Gp[NLEV][16];  // Gp[m] = A^(2^(6+m)) in f32
  __shared__ float4 S[NSEG];
  build_cols(M, C, K, dtp, nullptr, nullptr, Ad);
  __syncthreads();

  int tid = threadIdx.x;
  // lanes 0..15 of wave 0: 16 shuffle-squarings of A in f64, element (i,j) per lane
  if (tid < 16) {
    double m = Ad[tid];
    int i = tid >> 2, j = tid & 3;
#pragma unroll
    for (int lvl = 1; lvl <= SMAX; ++lvl) {
      double acc = 0.0;
#pragma unroll
      for (int k = 0; k < 4; ++k)
        acc += __shfl(m, i * 4 + k) * __shfl(m, k * 4 + j);
      m = acc;
      if (lvl >= L_LOG2) Gp[lvl - L_LOG2][tid] = (float)m;
    }
  }
  __syncthreads();

  float G[16];
#pragma unroll
  for (int e = 0; e < 16; ++e) G[e] = Gp[0][e];  // G = A^64 (per-chunk matrix)

  // segment combine: o_i = c[8i+7] + G c[8i+6] + ... + G^7 c[8i]
  float4 cj[SEG];
  int sbase = tid * SEG;
#pragma unroll
  for (int r = 0; r < SEG; ++r) cj[r] = c_arr[sbase + r];
  float4 o = cj[0];
#pragma unroll
  for (int r = 1; r < SEG; ++r) o = f4add(mv4(G, o), cj[r]);

  if (tid == 0) {  // fold initial state into segment 0: o0' = G^8 s0 + o0
    float4 s0 = make_float4(x0[0], x0[2], x0[1], x0[3]);
    o = f4add(mv4(&Gp[3][0], s0), o);  // Gp[3] = A^512 = G^8
  }
  S[tid] = o;
  __syncthreads();

  // Hillis-Steele inclusive scan: level k weight = (G^8)^(2^k) = Gp[3+k]
#pragma unroll
  for (int k = 0; k < 8; ++k) {
    int off = 1 << k;
    float4 add = make_float4(0.f, 0.f, 0.f, 0.f);
    bool act = (tid >= off);
    if (act) add = mv4(&Gp[3 + k][0], S[tid - off]);
    __syncthreads();
    if (act) S[tid] = f4add(S[tid], add);
    __syncthreads();
  }

  // expand segment start -> 8 chunk start states
  float4 st;
  if (tid == 0) st = make_float4(x0[0], x0[2], x0[1], x0[3]);
  else          st = S[tid - 1];
#pragma unroll
  for (int r = 0; r < SEG; ++r) {
    s_arr[sbase + r] = st;
    st = f4add(mv4(G, st), cj[r]);
  }
}

// ---------------- Kernel C: re-integrate chunks from boundary states, emit y ----------------
__global__ __launch_bounds__(256) void kEmit(
    const float* __restrict__ u, const float* M, const float* C, const float* K,
    const float* dtp, int T, const float4* __restrict__ s_arr, float2* __restrict__ out) {
  __shared__ float Af[16], Bf[8];
  build_cols(M, C, K, dtp, Af, Bf, nullptr);
  __syncthreads();
  float a[16], b[8];
#pragma unroll
  for (int e = 0; e < 16; ++e) a[e] = Af[e];
#pragma unroll
  for (int e = 0; e < 8; ++e) b[e] = Bf[e];

  int j  = blockIdx.x * blockDim.x + threadIdx.x;
  int t0 = j * L_CHUNK;
  const float2* u2 = (const float2*)u;
  float4 s = s_arr[j];
  if (t0 + L_CHUNK <= T) {
#pragma unroll 4
    for (int i = 0; i < L_CHUNK; ++i) {
      int t = t0 + i;
      s = stepf(a, b, s, u2[t]);
      out[t] = make_float2(s.x, s.y);
    }
  } else {
    for (int i = 0; i < L_CHUNK; ++i) {
      int t = t0 + i;
      if (t >= T) break;
      s = stepf(a, b, s, u2[t]);
      out[t] = make_float2(s.x, s.y);
    }
  }
}

// ---------------- fallback: exact serial f64 (only if ws too small / T too big) ----------------
__global__ void kSerialAll(const float* u, const float* Mp, const float* Cp, const float* Kp,
                           const float* dtp, const float* x0, int T, float2* out) {
  if (threadIdx.x != 0 || blockIdx.x != 0) return;
  double M[2]  = {(double)Mp[0], (double)Mp[1]};
  double Cm[4] = {(double)Cp[0] + (double)Cp[1], -(double)Cp[1],
                  -(double)Cp[1], (double)Cp[2] + (double)Cp[1]};
  double Km[4] = {(double)Kp[0] + (double)Kp[1], -(double)Kp[1],
                  -(double)Kp[1], (double)Kp[2] + (double)Kp[1]};
  double dt = (double)dtp[0];
  double y[2] = {(double)x0[0], (double)x0[2]};
  double v[2] = {(double)x0[1], (double)x0[3]};
  for (int t = 0; t < T; ++t) {
    double uu[2] = {(double)u[2 * t], (double)u[2 * t + 1]};
    rk4_step_d(M, Cm, Km, dt, y, v, uu);
    out[t] = make_float2((float)y[0], (float)y[1]);
  }
}

extern "C" void kernel_launch(void* const* d_in, const int* in_sizes, int n_in,
                              void* d_out, int out_size, void* d_ws, size_t ws_size,
                              hipStream_t stream) {
  (void)n_in; (void)out_size;
  const float* u   = (const float*)d_in[0];
  const float* M   = (const float*)d_in[1];
  const float* C   = (const float*)d_in[2];
  const float* K   = (const float*)d_in[3];
  const float* x0  = (const float*)d_in[4];
  const float* dt  = (const float*)d_in[5];
  int T = in_sizes[0] / 2;
  float2* out = (float2*)d_out;

  size_t need = (size_t)2 * NCHUNK * sizeof(float4);  // c_arr + s_arr = 64 KB
  if (ws_size < need || T > NCHUNK * L_CHUNK) {
    kSerialAll<<<1, 64, 0, stream>>>(u, M, C, K, dt, x0, T, out);
    return;
  }
  float4* c_arr = (float4*)d_ws;
  float4* s_arr = c_arr + NCHUNK;

  kOffsets<<<NCHUNK / 256, 256, 0, stream>>>(u, M, C, K, dt, T, c_arr);
  kScan<<<1, NSEG, 0, stream>>>(M, C, K, dt, x0, T, c_arr, s_arr);
  kEmit<<<NCHUNK / 256, 256, 0, stream>>>(u, M, C, K, dt, T, s_arr, out);
}

// Round 2
// 82.717 us; speedup vs baseline: 1.1164x; 1.1164x over previous
//
#include <hip/hip_runtime.h>

// Affine-scan parallelization of a linear RK4 recurrence.
// s = [y0, y1, v0, v1];  s_{t+1} = A s_t + B u_t  (A 4x4, B 4x2 constant).
//
// Round-2 structure: LSTEP=16 steps/chunk (chain 4x shorter than round 1),
// NCHPAD = 6400 chunks = 256 scan threads x SEG 25. All transition matrices
// built exactly in f64 (one-step map + shuffle pow-by-squaring), propagated f32.

#define LSTEP    16
#define SEG      25
#define NSEG     256
#define NCHPAD   (NSEG * SEG)   // 6400 chunks -> T up to 102400

// ---------------- f64 exact one-step RK4 map ----------------
__device__ inline void accel_d(const double* M, const double* Cm, const double* Km,
                               const double* u, const double* z, const double* v, double* a) {
  a[0] = (u[0] - Cm[0] * v[0] - Cm[1] * v[1] - Km[0] * z[0] - Km[1] * z[1]) / M[0];
  a[1] = (u[1] - Cm[2] * v[0] - Cm[3] * v[1] - Km[2] * z[0] - Km[3] * z[1]) / M[1];
}

__device__ inline void rk4_step_d(const double* M, const double* Cm, const double* Km,
                                  double dt, double* y, double* v, const double* u) {
  double k1[2], k2[2], k3[2], k4[2];
  double y2[2], v2[2], y3[2], v3[2], y4[2], v4[2];
  double h = dt * 0.5;
  accel_d(M, Cm, Km, u, y, v, k1);
  y2[0] = y[0] + v[0] * h;  y2[1] = y[1] + v[1] * h;
  v2[0] = v[0] + k1[0] * h; v2[1] = v[1] + k1[1] * h;
  accel_d(M, Cm, Km, u, y2, v2, k2);
  y3[0] = y[0] + v2[0] * h;  y3[1] = y[1] + v2[1] * h;
  v3[0] = v[0] + k2[0] * h;  v3[1] = v[1] + k2[1] * h;
  accel_d(M, Cm, Km, u, y3, v3, k3);
  y4[0] = y[0] + v3[0] * dt; y4[1] = y[1] + v3[1] * dt;
  v4[0] = v[0] + k3[0] * dt; v4[1] = v[1] + k3[1] * dt;
  accel_d(M, Cm, Km, u, y4, v4, k4);
  double s = dt / 6.0;
  double yn0 = y[0] + s * (v[0] + 2.0 * v2[0] + 2.0 * v3[0] + v4[0]);
  double yn1 = y[1] + s * (v[1] + 2.0 * v2[1] + 2.0 * v3[1] + v4[1]);
  double vn0 = v[0] + s * (k1[0] + 2.0 * k2[0] + 2.0 * k3[0] + k4[0]);
  double vn1 = v[1] + s * (k1[1] + 2.0 * k2[1] + 2.0 * k3[1] + k4[1]);
  y[0] = yn0; y[1] = yn1; v[0] = vn0; v[1] = vn1;
}

// threads 0..5 build columns of A (basis states) / B (basis inputs) in f64.
__device__ inline void build_cols(const float* Mp, const float* Cp, const float* Kp,
                                  const float* dtp, float* Af, float* Bf, double* Ad) {
  int tid = threadIdx.x;
  if (tid < 6) {
    double M[2]  = {(double)Mp[0], (double)Mp[1]};
    double Cm[4] = {(double)Cp[0] + (double)Cp[1], -(double)Cp[1],
                    -(double)Cp[1], (double)Cp[2] + (double)Cp[1]};
    double Km[4] = {(double)Kp[0] + (double)Kp[1], -(double)Kp[1],
                    -(double)Kp[1], (double)Kp[2] + (double)Kp[1]};
    double dt = (double)dtp[0];
    double y[2] = {0, 0}, v[2] = {0, 0}, u[2] = {0, 0};
    if      (tid == 0) y[0] = 1.0;
    else if (tid == 1) y[1] = 1.0;
    else if (tid == 2) v[0] = 1.0;
    else if (tid == 3) v[1] = 1.0;
    else if (tid == 4) u[0] = 1.0;
    else               u[1] = 1.0;
    rk4_step_d(M, Cm, Km, dt, y, v, u);
    if (tid < 4) {
      if (Af) {
        Af[0 * 4 + tid] = (float)y[0]; Af[1 * 4 + tid] = (float)y[1];
        Af[2 * 4 + tid] = (float)v[0]; Af[3 * 4 + tid] = (float)v[1];
      }
      if (Ad) {
        Ad[0 * 4 + tid] = y[0]; Ad[1 * 4 + tid] = y[1];
        Ad[2 * 4 + tid] = v[0]; Ad[3 * 4 + tid] = v[1];
      }
    } else if (Bf) {
      int j = tid - 4;
      Bf[0 * 2 + j] = (float)y[0]; Bf[1 * 2 + j] = (float)y[1];
      Bf[2 * 2 + j] = (float)v[0]; Bf[3 * 2 + j] = (float)v[1];
    }
  }
}

// ---------------- f32 helpers ----------------
__device__ inline float4 mv4(const float* A, float4 x) {
  float4 r;
  r.x = A[0]  * x.x + A[1]  * x.y + A[2]  * x.z + A[3]  * x.w;
  r.y = A[4]  * x.x + A[5]  * x.y + A[6]  * x.z + A[7]  * x.w;
  r.z = A[8]  * x.x + A[9]  * x.y + A[10] * x.z + A[11] * x.w;
  r.w = A[12] * x.x + A[13] * x.y + A[14] * x.z + A[15] * x.w;
  return r;
}
__device__ inline float4 f4add(float4 a, float4 b) {
  return make_float4(a.x + b.x, a.y + b.y, a.z + b.z, a.w + b.w);
}
__device__ inline float4 stepf(const float* a, const float* b, float4 s, float2 ut) {
  float4 r;
  r.x = a[0]  * s.x + a[1]  * s.y + a[2]  * s.z + a[3]  * s.w + b[0] * ut.x + b[1] * ut.y;
  r.y = a[4]  * s.x + a[5]  * s.y + a[6]  * s.z + a[7]  * s.w + b[2] * ut.x + b[3] * ut.y;
  r.z = a[8]  * s.x + a[9]  * s.y + a[10] * s.z + a[11] * s.w + b[4] * ut.x + b[5] * ut.y;
  r.w = a[12] * s.x + a[13] * s.y + a[14] * s.z + a[15] * s.w + b[6] * ut.x + b[7] * ut.y;
  return r;
}

// 4x4 f64 matmul across lanes 0..15 of a wave; lane holds element (i,j).
__device__ inline double matmul16(double a, double b, int i, int j) {
  double acc = 0.0;
#pragma unroll
  for (int k = 0; k < 4; ++k)
    acc += __shfl(a, i * 4 + k) * __shfl(b, k * 4 + j);
  return acc;
}

// ---------------- Kernel A: per-chunk affine offsets (zero start) ----------------
__global__ __launch_bounds__(256) void kOffsets(
    const float* __restrict__ u, const float* M, const float* C, const float* K,
    const float* dtp, int T, float4* __restrict__ c_arr) {
  __shared__ float Af[16], Bf[8];
  build_cols(M, C, K, dtp, Af, Bf, nullptr);
  __syncthreads();
  float a[16], b[8];
#pragma unroll
  for (int e = 0; e < 16; ++e) a[e] = Af[e];
#pragma unroll
  for (int e = 0; e < 8; ++e) b[e] = Bf[e];

  int j  = blockIdx.x * blockDim.x + threadIdx.x;  // chunk id
  int t0 = j * LSTEP;
  float4 c = make_float4(0.f, 0.f, 0.f, 0.f);
  if (t0 + LSTEP <= T) {
    const float4* u4 = (const float4*)(u + 2 * t0);  // 16j float2 -> 128B aligned
#pragma unroll
    for (int i = 0; i < LSTEP / 2; ++i) {
      float4 uu = u4[i];
      c = stepf(a, b, c, make_float2(uu.x, uu.y));
      c = stepf(a, b, c, make_float2(uu.z, uu.w));
    }
  } else {
    const float2* u2 = (const float2*)u;
    for (int i = 0; i < LSTEP; ++i) {
      int t = t0 + i;
      if (t >= T) break;
      c = stepf(a, b, c, u2[t]);
    }
  }
  c_arr[j] = c;  // empty chunks write 0 (identity offset)
}

// ---------------- Kernel B: power table + block scan -> chunk start states ----------------
__global__ __launch_bounds__(NSEG) void kScan(
    const float* M, const float* C, const float* K, const float* dtp,
    const float* x0, int T, const float4* __restrict__ c_arr, float4* __restrict__ s_arr) {
  __shared__ double Ad[16];
  __shared__ float  Gs[16];      // A^16 f32 (per-chunk matrix)
  __shared__ float  Wp[8][16];   // Wp[k] = (A^400)^(2^k) f32 (scan level weights)
  __shared__ float4 S[NSEG];
  build_cols(M, C, K, dtp, nullptr, nullptr, Ad);
  __syncthreads();

  int tid = threadIdx.x;
  if (tid < 16) {
    int i = tid >> 2, jj = tid & 3;
    double m = Ad[tid];
#pragma unroll
    for (int l = 0; l < 4; ++l) m = matmul16(m, m, i, jj);   // A^16
    Gs[tid] = (float)m;
    double t1 = m;
    double t2  = matmul16(t1, t1, i, jj);    // A^32
    double t4  = matmul16(t2, t2, i, jj);    // A^64
    double t8  = matmul16(t4, t4, i, jj);    // A^128
    double t16 = matmul16(t8, t8, i, jj);    // A^256
    double w = matmul16(matmul16(t16, t8, i, jj), t1, i, jj); // A^16^25 = A^400
    Wp[0][tid] = (float)w;
#pragma unroll
    for (int k = 1; k < 8; ++k) { w = matmul16(w, w, i, jj); Wp[k][tid] = (float)w; }
  }
  __syncthreads();

  float G[16];
#pragma unroll
  for (int e = 0; e < 16; ++e) G[e] = Gs[e];

  // segment combine over SEG consecutive chunks
  float4 cj[SEG];
  int sbase = tid * SEG;
#pragma unroll
  for (int r = 0; r < SEG; ++r) cj[r] = c_arr[sbase + r];
  float4 o = cj[0];
#pragma unroll
  for (int r = 1; r < SEG; ++r) o = f4add(mv4(G, o), cj[r]);

  float4 s0 = make_float4(x0[0], x0[2], x0[1], x0[3]);
  if (tid == 0) o = f4add(mv4(&Wp[0][0], s0), o);  // fold initial state into seg 0
  S[tid] = o;
  __syncthreads();

  // Hillis-Steele inclusive scan, level k weight = (A^400)^(2^k)
#pragma unroll
  for (int k = 0; k < 8; ++k) {
    int off = 1 << k;
    float4 add = make_float4(0.f, 0.f, 0.f, 0.f);
    bool act = (tid >= off);
    if (act) add = mv4(&Wp[k][0], S[tid - off]);
    __syncthreads();
    if (act) S[tid] = f4add(S[tid], add);
    __syncthreads();
  }

  // expand segment start -> SEG chunk start states
  float4 st = (tid == 0) ? s0 : S[tid - 1];
#pragma unroll
  for (int r = 0; r < SEG; ++r) {
    s_arr[sbase + r] = st;
    st = f4add(mv4(G, st), cj[r]);
  }
}

// ---------------- Kernel C: re-integrate chunks from boundary states, emit y ----------------
__global__ __launch_bounds__(256) void kEmit(
    const float* __restrict__ u, const float* M, const float* C, const float* K,
    const float* dtp, int T, const float4* __restrict__ s_arr, float2* __restrict__ out) {
  __shared__ float Af[16], Bf[8];
  build_cols(M, C, K, dtp, Af, Bf, nullptr);
  __syncthreads();
  float a[16], b[8];
#pragma unroll
  for (int e = 0; e < 16; ++e) a[e] = Af[e];
#pragma unroll
  for (int e = 0; e < 8; ++e) b[e] = Bf[e];

  int j  = blockIdx.x * blockDim.x + threadIdx.x;
  int t0 = j * LSTEP;
  float4 s = s_arr[j];
  if (t0 + LSTEP <= T) {
    const float4* u4 = (const float4*)(u + 2 * t0);
    float4* o4 = (float4*)(out + t0);  // 128B-aligned
#pragma unroll
    for (int i = 0; i < LSTEP / 2; ++i) {
      float4 uu = u4[i];
      s = stepf(a, b, s, make_float2(uu.x, uu.y));
      float2 ya = make_float2(s.x, s.y);
      s = stepf(a, b, s, make_float2(uu.z, uu.w));
      o4[i] = make_float4(ya.x, ya.y, s.x, s.y);
    }
  } else {
    const float2* u2 = (const float2*)u;
    for (int i = 0; i < LSTEP; ++i) {
      int t = t0 + i;
      if (t >= T) break;
      s = stepf(a, b, s, u2[t]);
      out[t] = make_float2(s.x, s.y);
    }
  }
}

// ---------------- fallback: exact serial f64 (only if ws too small / T too big) ----------------
__global__ void kSerialAll(const float* u, const float* Mp, const float* Cp, const float* Kp,
                           const float* dtp, const float* x0, int T, float2* out) {
  if (threadIdx.x != 0 || blockIdx.x != 0) return;
  double M[2]  = {(double)Mp[0], (double)Mp[1]};
  double Cm[4] = {(double)Cp[0] + (double)Cp[1], -(double)Cp[1],
                  -(double)Cp[1], (double)Cp[2] + (double)Cp[1]};
  double Km[4] = {(double)Kp[0] + (double)Kp[1], -(double)Kp[1],
                  -(double)Kp[1], (double)Kp[2] + (double)Kp[1]};
  double dt = (double)dtp[0];
  double y[2] = {(double)x0[0], (double)x0[2]};
  double v[2] = {(double)x0[1], (double)x0[3]};
  for (int t = 0; t < T; ++t) {
    double uu[2] = {(double)u[2 * t], (double)u[2 * t + 1]};
    rk4_step_d(M, Cm, Km, dt, y, v, uu);
    out[t] = make_float2((float)y[0], (float)y[1]);
  }
}

extern "C" void kernel_launch(void* const* d_in, const int* in_sizes, int n_in,
                              void* d_out, int out_size, void* d_ws, size_t ws_size,
                              hipStream_t stream) {
  (void)n_in; (void)out_size;
  const float* u   = (const float*)d_in[0];
  const float* M   = (const float*)d_in[1];
  const float* C   = (const float*)d_in[2];
  const float* K   = (const float*)d_in[3];
  const float* x0  = (const float*)d_in[4];
  const float* dt  = (const float*)d_in[5];
  int T = in_sizes[0] / 2;
  float2* out = (float2*)d_out;

  size_t need = (size_t)2 * NCHPAD * sizeof(float4);  // c_arr + s_arr = 200 KB
  if (ws_size < need || T > NCHPAD * LSTEP) {
    kSerialAll<<<1, 64, 0, stream>>>(u, M, C, K, dt, x0, T, out);
    return;
  }
  float4* c_arr = (float4*)d_ws;
  float4* s_arr = c_arr + NCHPAD;

  kOffsets<<<NCHPAD / 256, 256, 0, stream>>>(u, M, C, K, dt, T, c_arr);
  kScan<<<1, NSEG, 0, stream>>>(M, C, K, dt, x0, T, c_arr, s_arr);
  kEmit<<<NCHPAD / 256, 256, 0, stream>>>(u, M, C, K, dt, T, s_arr, out);
}

// Round 3
// 81.223 us; speedup vs baseline: 1.1370x; 1.0184x over previous
//
#include <hip/hip_runtime.h>

// Fused single-pass affine-scan RK4 integrator (decoupled lookback).
// s = [y0, y1, v0, v1];  s_{t+1} = A s_t + B u_t  (A 4x4, B 4x2 constant).
//
// One kernel: per-thread 16-step chunk offset (u held in regs) -> block
// weighted scan -> publish aggregate + flag (agent scope; ws 0xAA poison is
// the "not ready" state) -> lookback over predecessors -> second scan to
// place each chunk's start state -> emit from registers.

#define LSTEP  16
#define TPB    256
#define MAXNB  256   // ws slots for aggregates/flags; covers T <= 1,048,576

// ---------------- f64 exact one-step RK4 map ----------------
__device__ inline void accel_d(const double* M, const double* Cm, const double* Km,
                               const double* u, const double* z, const double* v, double* a) {
  a[0] = (u[0] - Cm[0] * v[0] - Cm[1] * v[1] - Km[0] * z[0] - Km[1] * z[1]) / M[0];
  a[1] = (u[1] - Cm[2] * v[0] - Cm[3] * v[1] - Km[2] * z[0] - Km[3] * z[1]) / M[1];
}

__device__ inline void rk4_step_d(const double* M, const double* Cm, const double* Km,
                                  double dt, double* y, double* v, const double* u) {
  double k1[2], k2[2], k3[2], k4[2];
  double y2[2], v2[2], y3[2], v3[2], y4[2], v4[2];
  double h = dt * 0.5;
  accel_d(M, Cm, Km, u, y, v, k1);
  y2[0] = y[0] + v[0] * h;  y2[1] = y[1] + v[1] * h;
  v2[0] = v[0] + k1[0] * h; v2[1] = v[1] + k1[1] * h;
  accel_d(M, Cm, Km, u, y2, v2, k2);
  y3[0] = y[0] + v2[0] * h;  y3[1] = y[1] + v2[1] * h;
  v3[0] = v[0] + k2[0] * h;  v3[1] = v[1] + k2[1] * h;
  accel_d(M, Cm, Km, u, y3, v3, k3);
  y4[0] = y[0] + v3[0] * dt; y4[1] = y[1] + v3[1] * dt;
  v4[0] = v[0] + k3[0] * dt; v4[1] = v[1] + k3[1] * dt;
  accel_d(M, Cm, Km, u, y4, v4, k4);
  double s = dt / 6.0;
  double yn0 = y[0] + s * (v[0] + 2.0 * v2[0] + 2.0 * v3[0] + v4[0]);
  double yn1 = y[1] + s * (v[1] + 2.0 * v2[1] + 2.0 * v3[1] + v4[1]);
  double vn0 = v[0] + s * (k1[0] + 2.0 * k2[0] + 2.0 * k3[0] + k4[0]);
  double vn1 = v[1] + s * (k1[1] + 2.0 * k2[1] + 2.0 * k3[1] + k4[1]);
  y[0] = yn0; y[1] = yn1; v[0] = vn0; v[1] = vn1;
}

// threads 0..5 build columns of A (basis states) / B (basis inputs) in f64.
__device__ inline void build_cols(const float* Mp, const float* Cp, const float* Kp,
                                  const float* dtp, float* Af, float* Bf, double* Ad) {
  int tid = threadIdx.x;
  if (tid < 6) {
    double M[2]  = {(double)Mp[0], (double)Mp[1]};
    double Cm[4] = {(double)Cp[0] + (double)Cp[1], -(double)Cp[1],
                    -(double)Cp[1], (double)Cp[2] + (double)Cp[1]};
    double Km[4] = {(double)Kp[0] + (double)Kp[1], -(double)Kp[1],
                    -(double)Kp[1], (double)Kp[2] + (double)Kp[1]};
    double dt = (double)dtp[0];
    double y[2] = {0, 0}, v[2] = {0, 0}, u[2] = {0, 0};
    if      (tid == 0) y[0] = 1.0;
    else if (tid == 1) y[1] = 1.0;
    else if (tid == 2) v[0] = 1.0;
    else if (tid == 3) v[1] = 1.0;
    else if (tid == 4) u[0] = 1.0;
    else               u[1] = 1.0;
    rk4_step_d(M, Cm, Km, dt, y, v, u);
    if (tid < 4) {
      if (Af) {
        Af[0 * 4 + tid] = (float)y[0]; Af[1 * 4 + tid] = (float)y[1];
        Af[2 * 4 + tid] = (float)v[0]; Af[3 * 4 + tid] = (float)v[1];
      }
      if (Ad) {
        Ad[0 * 4 + tid] = y[0]; Ad[1 * 4 + tid] = y[1];
        Ad[2 * 4 + tid] = v[0]; Ad[3 * 4 + tid] = v[1];
      }
    } else if (Bf) {
      int j = tid - 4;
      Bf[0 * 2 + j] = (float)y[0]; Bf[1 * 2 + j] = (float)y[1];
      Bf[2 * 2 + j] = (float)v[0]; Bf[3 * 2 + j] = (float)v[1];
    }
  }
}

// ---------------- f32 helpers ----------------
__device__ inline float4 mv4(const float* A, float4 x) {
  float4 r;
  r.x = A[0]  * x.x + A[1]  * x.y + A[2]  * x.z + A[3]  * x.w;
  r.y = A[4]  * x.x + A[5]  * x.y + A[6]  * x.z + A[7]  * x.w;
  r.z = A[8]  * x.x + A[9]  * x.y + A[10] * x.z + A[11] * x.w;
  r.w = A[12] * x.x + A[13] * x.y + A[14] * x.z + A[15] * x.w;
  return r;
}
__device__ inline float4 f4add(float4 a, float4 b) {
  return make_float4(a.x + b.x, a.y + b.y, a.z + b.z, a.w + b.w);
}
__device__ inline float4 stepf(const float* a, const float* b, float4 s, float2 ut) {
  float4 r;
  r.x = a[0]  * s.x + a[1]  * s.y + a[2]  * s.z + a[3]  * s.w + b[0] * ut.x + b[1] * ut.y;
  r.y = a[4]  * s.x + a[5]  * s.y + a[6]  * s.z + a[7]  * s.w + b[2] * ut.x + b[3] * ut.y;
  r.z = a[8]  * s.x + a[9]  * s.y + a[10] * s.z + a[11] * s.w + b[4] * ut.x + b[5] * ut.y;
  r.w = a[12] * s.x + a[13] * s.y + a[14] * s.z + a[15] * s.w + b[6] * ut.x + b[7] * ut.y;
  return r;
}

// 4x4 f64 matmul across lanes 0..15 of wave 0; lane holds element (i,j).
__device__ inline double matmul16(double a, double b, int i, int j) {
  double acc = 0.0;
#pragma unroll
  for (int k = 0; k < 4; ++k)
    acc += __shfl(a, i * 4 + k) * __shfl(b, k * 4 + j);
  return acc;
}

// ---------------- fused kernel ----------------
__global__ __launch_bounds__(TPB) void kFused(
    const float* __restrict__ u, const float* M, const float* C, const float* K,
    const float* dtp, const float* x0, int T,
    float4* __restrict__ agg, int* __restrict__ flags, float2* __restrict__ out) {
  __shared__ float  Af[16], Bf[8];
  __shared__ double Ad[16];
  __shared__ float  Wlev[8][16];  // A^(16*2^k), k=0..7
  __shared__ float  Wf[16];       // A^4096 (block-to-block hop)
  __shared__ float4 S[TPB];
  __shared__ float4 sB;

  int tid = threadIdx.x;
  int b   = blockIdx.x;

  build_cols(M, C, K, dtp, Af, Bf, Ad);
  __syncthreads();

  if (tid < 16) {
    int i = tid >> 2, jj = tid & 3;
    double m = Ad[tid];
#pragma unroll
    for (int l = 0; l < 4; ++l) m = matmul16(m, m, i, jj);   // A^16
    Wlev[0][tid] = (float)m;
#pragma unroll
    for (int k = 1; k < 8; ++k) { m = matmul16(m, m, i, jj); Wlev[k][tid] = (float)m; }
    m = matmul16(m, m, i, jj);                                // A^4096
    Wf[tid] = (float)m;
  }
  __syncthreads();

  float a[16], bb[8];
#pragma unroll
  for (int e = 0; e < 16; ++e) a[e] = Af[e];
#pragma unroll
  for (int e = 0; e < 8; ++e) bb[e] = Bf[e];

  // ---- phase 1: chunk offset from zero start; u held in registers ----
  int j  = b * TPB + tid;
  int t0 = j * LSTEP;
  bool full = (t0 + LSTEP <= T);
  float4 uu[LSTEP / 2];
  float4 c = make_float4(0.f, 0.f, 0.f, 0.f);
  if (full) {
    const float4* u4 = (const float4*)(u + 2 * t0);
#pragma unroll
    for (int i = 0; i < LSTEP / 2; ++i) uu[i] = u4[i];
#pragma unroll
    for (int i = 0; i < LSTEP / 2; ++i) {
      c = stepf(a, bb, c, make_float2(uu[i].x, uu[i].y));
      c = stepf(a, bb, c, make_float2(uu[i].z, uu[i].w));
    }
  } else {
    const float2* u2 = (const float2*)u;
    for (int i = 0; i < LSTEP; ++i) {
      int t = t0 + i;
      if (t >= T) break;
      c = stepf(a, bb, c, u2[t]);
    }
  }

  // ---- phase 2: block-internal weighted inclusive scan (zero start) ----
  S[tid] = c;
  __syncthreads();
#pragma unroll
  for (int k = 0; k < 8; ++k) {
    int off = 1 << k;
    float4 add = make_float4(0.f, 0.f, 0.f, 0.f);
    bool act = (tid >= off);
    if (act) add = mv4(&Wlev[k][0], S[tid - off]);
    __syncthreads();
    if (act) S[tid] = f4add(S[tid], add);
    __syncthreads();
  }
  float4 E = (tid == 0) ? make_float4(0.f, 0.f, 0.f, 0.f) : S[tid - 1];  // exclusive prefix

  // ---- phase 3: publish aggregate, lookback (thread 0) ----
  if (tid == 0) {
    float4 s0v = make_float4(x0[0], x0[2], x0[1], x0[3]);
    float4 o = S[TPB - 1];
    if (b == 0) o = f4add(mv4(Wf, s0v), o);  // fold initial state into block 0's agg
    agg[b] = o;
    __threadfence();  // agent-scope release of the payload
    __hip_atomic_store(&flags[b], 1, __ATOMIC_RELEASE, __HIP_MEMORY_SCOPE_AGENT);

    float4 acc;
    if (b == 0) {
      acc = s0v;  // incoming state of block 0 is x0
    } else {
      acc = make_float4(0.f, 0.f, 0.f, 0.f);
      float Wk[16], Wl[16], t[16];
#pragma unroll
      for (int e = 0; e < 16; ++e) { Wk[e] = ((e & 5) == 0 && (e >> 2) == (e & 3)) ? 1.f : 0.f; }
#pragma unroll
      for (int e = 0; e < 16; ++e) { Wk[e] = ((e >> 2) == (e & 3)) ? 1.f : 0.f; Wl[e] = Wf[e]; }
      for (int p = b - 1; p >= 0; --p) {
        while (__hip_atomic_load(&flags[p], __ATOMIC_ACQUIRE, __HIP_MEMORY_SCOPE_AGENT) != 1) {}
        float4 op = agg[p];
        acc = f4add(acc, mv4(Wk, op));
        if (p > 0) {
#pragma unroll
          for (int i2 = 0; i2 < 4; ++i2)
#pragma unroll
            for (int j2 = 0; j2 < 4; ++j2)
              t[i2 * 4 + j2] = Wk[i2 * 4 + 0] * Wl[0 * 4 + j2] + Wk[i2 * 4 + 1] * Wl[1 * 4 + j2]
                             + Wk[i2 * 4 + 2] * Wl[2 * 4 + j2] + Wk[i2 * 4 + 3] * Wl[3 * 4 + j2];
#pragma unroll
          for (int e = 0; e < 16; ++e) Wk[e] = t[e];
        }
      }
    }
    sB = acc;
  }
  __syncthreads();

  // ---- phase 4: propagate incoming state to every chunk: X_tid = A^(16*tid) * sB ----
  S[tid] = (tid == 0) ? sB : make_float4(0.f, 0.f, 0.f, 0.f);
  __syncthreads();
#pragma unroll
  for (int k = 0; k < 8; ++k) {
    int off = 1 << k;
    float4 add = make_float4(0.f, 0.f, 0.f, 0.f);
    bool act = (tid >= off);
    if (act) add = mv4(&Wlev[k][0], S[tid - off]);
    __syncthreads();
    if (act) S[tid] = f4add(S[tid], add);
    __syncthreads();
  }
  float4 st = f4add(S[tid], E);  // chunk start state

  // ---- phase 5: emit from registers ----
  if (full) {
    float4* o4 = (float4*)(out + t0);
#pragma unroll
    for (int i = 0; i < LSTEP / 2; ++i) {
      st = stepf(a, bb, st, make_float2(uu[i].x, uu[i].y));
      float2 ya = make_float2(st.x, st.y);
      st = stepf(a, bb, st, make_float2(uu[i].z, uu[i].w));
      o4[i] = make_float4(ya.x, ya.y, st.x, st.y);
    }
  } else {
    const float2* u2 = (const float2*)u;
    for (int i = 0; i < LSTEP; ++i) {
      int t = t0 + i;
      if (t >= T) break;
      st = stepf(a, bb, st, u2[t]);
      out[t] = make_float2(st.x, st.y);
    }
  }
}

// ---------------- fallback: exact serial f64 ----------------
__global__ void kSerialAll(const float* u, const float* Mp, const float* Cp, const float* Kp,
                           const float* dtp, const float* x0, int T, float2* out) {
  if (threadIdx.x != 0 || blockIdx.x != 0) return;
  double M[2]  = {(double)Mp[0], (double)Mp[1]};
  double Cm[4] = {(double)Cp[0] + (double)Cp[1], -(double)Cp[1],
                  -(double)Cp[1], (double)Cp[2] + (double)Cp[1]};
  double Km[4] = {(double)Kp[0] + (double)Kp[1], -(double)Kp[1],
                  -(double)Kp[1], (double)Kp[2] + (double)Kp[1]};
  double dt = (double)dtp[0];
  double y[2] = {(double)x0[0], (double)x0[2]};
  double v[2] = {(double)x0[1], (double)x0[3]};
  for (int t = 0; t < T; ++t) {
    double uu[2] = {(double)u[2 * t], (double)u[2 * t + 1]};
    rk4_step_d(M, Cm, Km, dt, y, v, uu);
    out[t] = make_float2((float)y[0], (float)y[1]);
  }
}

extern "C" void kernel_launch(void* const* d_in, const int* in_sizes, int n_in,
                              void* d_out, int out_size, void* d_ws, size_t ws_size,
                              hipStream_t stream) {
  (void)n_in; (void)out_size;
  const float* u   = (const float*)d_in[0];
  const float* M   = (const float*)d_in[1];
  const float* C   = (const float*)d_in[2];
  const float* K   = (const float*)d_in[3];
  const float* x0  = (const float*)d_in[4];
  const float* dt  = (const float*)d_in[5];
  int T = in_sizes[0] / 2;
  float2* out = (float2*)d_out;

  int nch = (T + LSTEP - 1) / LSTEP;
  int nb  = (nch + TPB - 1) / TPB;
  size_t need = (size_t)MAXNB * (sizeof(float4) + sizeof(int));
  if (nb > MAXNB || ws_size < need) {
    kSerialAll<<<1, 64, 0, stream>>>(u, M, C, K, dt, x0, T, out);
    return;
  }
  float4* agg  = (float4*)d_ws;
  int* flags   = (int*)(agg + MAXNB);
  // ws is re-poisoned to 0xAA before every launch -> flags != 1 means "not ready";
  // no separate init pass needed.
  kFused<<<nb, TPB, 0, stream>>>(u, M, C, K, dt, x0, T, agg, flags, out);
}

// Round 4
// 76.491 us; speedup vs baseline: 1.2073x; 1.0619x over previous
//
#include <hip/hip_runtime.h>

// Fused single-pass affine-scan RK4 integrator, round 4.
// s = [y0, y1, v0, v1];  s_{t+1} = A s_t + B u_t  (A 4x4, B 4x2 constant).
//
// vs round 3: (a) wave-parallel lookback (lane p handles predecessor p with
// weight W^(b-1-p) from LDS table) replaces the serial predecessor walk;
// (b) the post-lookback 8-level scan is replaced by a one-mv4 placement using
// an LDS power table T[k] = A^(16k) built by log-doubling from f64-accurate
// power-of-two seeds. Critical path after sB: 1 mv4 + 16-step emit.

#define LSTEP  16
#define TPB    256
#define MAXNB  256   // ws slots; covers T <= 1,048,576

// ---------------- f64 exact one-step RK4 map ----------------
__device__ inline void accel_d(const double* M, const double* Cm, const double* Km,
                               const double* u, const double* z, const double* v, double* a) {
  a[0] = (u[0] - Cm[0] * v[0] - Cm[1] * v[1] - Km[0] * z[0] - Km[1] * z[1]) / M[0];
  a[1] = (u[1] - Cm[2] * v[0] - Cm[3] * v[1] - Km[2] * z[0] - Km[3] * z[1]) / M[1];
}

__device__ inline void rk4_step_d(const double* M, const double* Cm, const double* Km,
                                  double dt, double* y, double* v, const double* u) {
  double k1[2], k2[2], k3[2], k4[2];
  double y2[2], v2[2], y3[2], v3[2], y4[2], v4[2];
  double h = dt * 0.5;
  accel_d(M, Cm, Km, u, y, v, k1);
  y2[0] = y[0] + v[0] * h;  y2[1] = y[1] + v[1] * h;
  v2[0] = v[0] + k1[0] * h; v2[1] = v[1] + k1[1] * h;
  accel_d(M, Cm, Km, u, y2, v2, k2);
  y3[0] = y[0] + v2[0] * h;  y3[1] = y[1] + v2[1] * h;
  v3[0] = v[0] + k2[0] * h;  v3[1] = v[1] + k2[1] * h;
  accel_d(M, Cm, Km, u, y3, v3, k3);
  y4[0] = y[0] + v3[0] * dt; y4[1] = y[1] + v3[1] * dt;
  v4[0] = v[0] + k3[0] * dt; v4[1] = v[1] + k3[1] * dt;
  accel_d(M, Cm, Km, u, y4, v4, k4);
  double s = dt / 6.0;
  double yn0 = y[0] + s * (v[0] + 2.0 * v2[0] + 2.0 * v3[0] + v4[0]);
  double yn1 = y[1] + s * (v[1] + 2.0 * v2[1] + 2.0 * v3[1] + v4[1]);
  double vn0 = v[0] + s * (k1[0] + 2.0 * k2[0] + 2.0 * k3[0] + k4[0]);
  double vn1 = v[1] + s * (k1[1] + 2.0 * k2[1] + 2.0 * k3[1] + k4[1]);
  y[0] = yn0; y[1] = yn1; v[0] = vn0; v[1] = vn1;
}

// threads 0..5 build columns of A (basis states) / B (basis inputs) in f64.
__device__ inline void build_cols(const float* Mp, const float* Cp, const float* Kp,
                                  const float* dtp, float* Af, float* Bf, double* Ad) {
  int tid = threadIdx.x;
  if (tid < 6) {
    double M[2]  = {(double)Mp[0], (double)Mp[1]};
    double Cm[4] = {(double)Cp[0] + (double)Cp[1], -(double)Cp[1],
                    -(double)Cp[1], (double)Cp[2] + (double)Cp[1]};
    double Km[4] = {(double)Kp[0] + (double)Kp[1], -(double)Kp[1],
                    -(double)Kp[1], (double)Kp[2] + (double)Kp[1]};
    double dt = (double)dtp[0];
    double y[2] = {0, 0}, v[2] = {0, 0}, u[2] = {0, 0};
    if      (tid == 0) y[0] = 1.0;
    else if (tid == 1) y[1] = 1.0;
    else if (tid == 2) v[0] = 1.0;
    else if (tid == 3) v[1] = 1.0;
    else if (tid == 4) u[0] = 1.0;
    else               u[1] = 1.0;
    rk4_step_d(M, Cm, Km, dt, y, v, u);
    if (tid < 4) {
      Af[0 * 4 + tid] = (float)y[0]; Af[1 * 4 + tid] = (float)y[1];
      Af[2 * 4 + tid] = (float)v[0]; Af[3 * 4 + tid] = (float)v[1];
      Ad[0 * 4 + tid] = y[0]; Ad[1 * 4 + tid] = y[1];
      Ad[2 * 4 + tid] = v[0]; Ad[3 * 4 + tid] = v[1];
    } else {
      int j = tid - 4;
      Bf[0 * 2 + j] = (float)y[0]; Bf[1 * 2 + j] = (float)y[1];
      Bf[2 * 2 + j] = (float)v[0]; Bf[3 * 2 + j] = (float)v[1];
    }
  }
}

// ---------------- f32 helpers ----------------
__device__ inline float4 mv4(const float* A, float4 x) {
  float4 r;
  r.x = A[0]  * x.x + A[1]  * x.y + A[2]  * x.z + A[3]  * x.w;
  r.y = A[4]  * x.x + A[5]  * x.y + A[6]  * x.z + A[7]  * x.w;
  r.z = A[8]  * x.x + A[9]  * x.y + A[10] * x.z + A[11] * x.w;
  r.w = A[12] * x.x + A[13] * x.y + A[14] * x.z + A[15] * x.w;
  return r;
}
__device__ inline float4 f4add(float4 a, float4 b) {
  return make_float4(a.x + b.x, a.y + b.y, a.z + b.z, a.w + b.w);
}
__device__ inline float4 stepf(const float* a, const float* b, float4 s, float2 ut) {
  float4 r;
  r.x = a[0]  * s.x + a[1]  * s.y + a[2]  * s.z + a[3]  * s.w + b[0] * ut.x + b[1] * ut.y;
  r.y = a[4]  * s.x + a[5]  * s.y + a[6]  * s.z + a[7]  * s.w + b[2] * ut.x + b[3] * ut.y;
  r.z = a[8]  * s.x + a[9]  * s.y + a[10] * s.z + a[11] * s.w + b[4] * ut.x + b[5] * ut.y;
  r.w = a[12] * s.x + a[13] * s.y + a[14] * s.z + a[15] * s.w + b[6] * ut.x + b[7] * ut.y;
  return r;
}
// Z = X * Y (4x4 f32, row-major)
__device__ inline void mm4(const float* X, const float* Y, float* Z) {
#pragma unroll
  for (int i = 0; i < 4; ++i)
#pragma unroll
    for (int j = 0; j < 4; ++j)
      Z[i * 4 + j] = X[i * 4 + 0] * Y[0 * 4 + j] + X[i * 4 + 1] * Y[1 * 4 + j]
                   + X[i * 4 + 2] * Y[2 * 4 + j] + X[i * 4 + 3] * Y[3 * 4 + j];
}

// 4x4 f64 matmul across lanes 0..15 of wave 0; lane holds element (i,j).
__device__ inline double matmul16(double a, double b, int i, int j) {
  double acc = 0.0;
#pragma unroll
  for (int k = 0; k < 4; ++k)
    acc += __shfl(a, i * 4 + k) * __shfl(b, k * 4 + j);
  return acc;
}

// ---------------- fused kernel ----------------
__global__ __launch_bounds__(TPB) void kFused(
    const float* __restrict__ u, const float* M, const float* C, const float* K,
    const float* dtp, const float* x0, int T,
    float4* __restrict__ agg, int* __restrict__ flags, float2* __restrict__ out) {
  __shared__ float  Af[16], Bf[8];
  __shared__ double Ad[16];
  __shared__ float  Tt[256][16];  // Tt[k] = A^(16k)
  __shared__ float  Wt[32][16];   // Wt[k] = A^(4096k), k=0..24 used
  __shared__ float4 S[TPB];
  __shared__ float4 sBsh;

  int tid = threadIdx.x;
  int b   = blockIdx.x;

  // ---- issue u loads early (independent of all table building) ----
  int j  = b * TPB + tid;
  int t0 = j * LSTEP;
  bool full = (t0 + LSTEP <= T);
  float4 uu[LSTEP / 2];
  if (full) {
    const float4* u4 = (const float4*)(u + 2 * t0);
#pragma unroll
    for (int i = 0; i < LSTEP / 2; ++i) uu[i] = u4[i];
  }

  build_cols(M, C, K, dtp, Af, Bf, Ad);
  if (tid == 0) {
#pragma unroll
    for (int e = 0; e < 16; ++e) {
      float v = ((e >> 2) == (e & 3)) ? 1.f : 0.f;
      Tt[0][e] = v; Wt[0][e] = v;
    }
  }
  __syncthreads();

  // ---- f64 squaring chain: seed power-of-two entries of both tables ----
  if (tid < 16) {
    int i = tid >> 2, jj = tid & 3;
    double m = Ad[tid];
#pragma unroll
    for (int lvl = 1; lvl <= 16; ++lvl) {
      m = matmul16(m, m, i, jj);                       // m = A^(2^lvl)
      if (lvl >= 4 && lvl <= 11) Tt[1 << (lvl - 4)][tid] = (float)m;   // A^(16*2^(lvl-4))
      if (lvl >= 12)             Wt[1 << (lvl - 12)][tid] = (float)m;  // A^(4096*2^(lvl-12))
    }
  }
  __syncthreads();

  // ---- log-doubling fill of non-power entries ----
#pragma unroll
  for (int d = 1; d < 8; ++d) {
    int off = 1 << d;
    if (tid > off && tid < 2 * off)          // Tt[k] = Tt[k-off] * Tt[off]
      mm4(&Tt[tid - off][0], &Tt[off][0], &Tt[tid][0]);
    if (d <= 4) {                            // Wt fill via threads 128+k
      int k = tid - 128;
      if (k > off && k < 2 * off && k < 25 && tid >= 128 + off + 1)
        mm4(&Wt[k - off][0], &Wt[off][0], &Wt[k][0]);
    }
    __syncthreads();
  }

  float a[16], bb[8];
#pragma unroll
  for (int e = 0; e < 16; ++e) a[e] = Af[e];
#pragma unroll
  for (int e = 0; e < 8; ++e) bb[e] = Bf[e];

  // ---- phase 1: chunk offset from zero start (u in registers) ----
  float4 c = make_float4(0.f, 0.f, 0.f, 0.f);
  if (full) {
#pragma unroll
    for (int i = 0; i < LSTEP / 2; ++i) {
      c = stepf(a, bb, c, make_float2(uu[i].x, uu[i].y));
      c = stepf(a, bb, c, make_float2(uu[i].z, uu[i].w));
    }
  } else {
    const float2* u2 = (const float2*)u;
    for (int i = 0; i < LSTEP; ++i) {
      int t = t0 + i;
      if (t >= T) break;
      c = stepf(a, bb, c, u2[t]);
    }
  }

  // ---- phase 2: block weighted inclusive scan (weights Tt[2^k]) ----
  S[tid] = c;
  __syncthreads();
#pragma unroll
  for (int k = 0; k < 8; ++k) {
    int off = 1 << k;
    float4 add = make_float4(0.f, 0.f, 0.f, 0.f);
    bool act = (tid >= off);
    if (act) add = mv4(&Tt[off][0], S[tid - off]);
    __syncthreads();
    if (act) S[tid] = f4add(S[tid], add);
    __syncthreads();
  }
  float4 E = (tid == 0) ? make_float4(0.f, 0.f, 0.f, 0.f) : S[tid - 1];

  // ---- phase 3: publish aggregate; wave-parallel lookback ----
  float4 s0v = make_float4(x0[0], x0[2], x0[1], x0[3]);
  if (tid == 0) {
    float4 o = S[TPB - 1];
    if (b == 0) o = f4add(mv4(&Wt[1][0], s0v), o);  // fold x0 into block 0's agg
    agg[b] = o;
    __threadfence();
    __hip_atomic_store(&flags[b], 1, __ATOMIC_RELEASE, __HIP_MEMORY_SCOPE_AGENT);
  }
  float4 sB;
  if (b == 0) {
    sB = s0v;
  } else {
    if (tid < 64) {
      float4 acc = make_float4(0.f, 0.f, 0.f, 0.f);
      if (tid < b) {
        int p = tid;
        while (__hip_atomic_load(&flags[p], __ATOMIC_ACQUIRE, __HIP_MEMORY_SCOPE_AGENT) != 1) {}
        acc = mv4(&Wt[b - 1 - p][0], agg[p]);
      }
#pragma unroll
      for (int o2 = 32; o2 >= 1; o2 >>= 1) {
        acc.x += __shfl_xor(acc.x, o2);
        acc.y += __shfl_xor(acc.y, o2);
        acc.z += __shfl_xor(acc.z, o2);
        acc.w += __shfl_xor(acc.w, o2);
      }
      if (tid == 0) sBsh = acc;
    }
    __syncthreads();
    sB = sBsh;
  }

  // ---- phase 4: place chunk start state with one mv4 ----
  float4 st = f4add(mv4(&Tt[tid][0], sB), E);

  // ---- phase 5: emit from registers ----
  if (full) {
    float4* o4 = (float4*)(out + t0);
#pragma unroll
    for (int i = 0; i < LSTEP / 2; ++i) {
      st = stepf(a, bb, st, make_float2(uu[i].x, uu[i].y));
      float2 ya = make_float2(st.x, st.y);
      st = stepf(a, bb, st, make_float2(uu[i].z, uu[i].w));
      o4[i] = make_float4(ya.x, ya.y, st.x, st.y);
    }
  } else {
    const float2* u2 = (const float2*)u;
    for (int i = 0; i < LSTEP; ++i) {
      int t = t0 + i;
      if (t >= T) break;
      st = stepf(a, bb, st, u2[t]);
      out[t] = make_float2(st.x, st.y);
    }
  }
}

// ---------------- fallback: exact serial f64 ----------------
__global__ void kSerialAll(const float* u, const float* Mp, const float* Cp, const float* Kp,
                           const float* dtp, const float* x0, int T, float2* out) {
  if (threadIdx.x != 0 || blockIdx.x != 0) return;
  double M[2]  = {(double)Mp[0], (double)Mp[1]};
  double Cm[4] = {(double)Cp[0] + (double)Cp[1], -(double)Cp[1],
                  -(double)Cp[1], (double)Cp[2] + (double)Cp[1]};
  double Km[4] = {(double)Kp[0] + (double)Kp[1], -(double)Kp[1],
                  -(double)Kp[1], (double)Kp[2] + (double)Kp[1]};
  double dt = (double)dtp[0];
  double y[2] = {(double)x0[0], (double)x0[2]};
  double v[2] = {(double)x0[1], (double)x0[3]};
  for (int t = 0; t < T; ++t) {
    double uu[2] = {(double)u[2 * t], (double)u[2 * t + 1]};
    rk4_step_d(M, Cm, Km, dt, y, v, uu);
    out[t] = make_float2((float)y[0], (float)y[1]);
  }
}

extern "C" void kernel_launch(void* const* d_in, const int* in_sizes, int n_in,
                              void* d_out, int out_size, void* d_ws, size_t ws_size,
                              hipStream_t stream) {
  (void)n_in; (void)out_size;
  const float* u   = (const float*)d_in[0];
  const float* M   = (const float*)d_in[1];
  const float* C   = (const float*)d_in[2];
  const float* K   = (const float*)d_in[3];
  const float* x0  = (const float*)d_in[4];
  const float* dt  = (const float*)d_in[5];
  int T = in_sizes[0] / 2;
  float2* out = (float2*)d_out;

  int nch = (T + LSTEP - 1) / LSTEP;
  int nb  = (nch + TPB - 1) / TPB;
  size_t need = (size_t)MAXNB * (sizeof(float4) + sizeof(int));
  // wave-parallel lookback handles up to 64 predecessors (one wave)
  if (nb > 64 || ws_size < need) {
    kSerialAll<<<1, 64, 0, stream>>>(u, M, C, K, dt, x0, T, out);
    return;
  }
  float4* agg  = (float4*)d_ws;
  int* flags   = (int*)(agg + MAXNB);
  // ws is re-poisoned to 0xAA before every launch -> flags != 1 means "not ready".
  kFused<<<nb, TPB, 0, stream>>>(u, M, C, K, dt, x0, T, agg, flags, out);
}